// Round 17
// baseline (210.586 us; speedup 1.0000x reference)
//
#include <hip/hip_runtime.h>

typedef __attribute__((ext_vector_type(8))) short short8;
typedef __attribute__((ext_vector_type(4))) float f32x4;
typedef __attribute__((ext_vector_type(16))) float f32x16;

#define DEVFN __device__ __forceinline__

DEVFN unsigned short f2bf(float f) {
  unsigned int u = __builtin_bit_cast(unsigned int, f);
  u += 0x7FFFu + ((u >> 16) & 1u);   // RNE
  return (unsigned short)(u >> 16);
}
DEVFN float bf2f(unsigned int u) { return __builtin_bit_cast(float, u << 16); }

DEVFN unsigned int cvtpk_bf16(float lo, float hi) {
  unsigned int d;
  asm("v_cvt_pk_bf16_f32 %0, %1, %2" : "=v"(d) : "v"(lo), "v"(hi));
  return d;
}
DEVFN void plswap32(unsigned int& a, unsigned int& b) {
  asm("v_permlane32_swap_b32 %0, %1" : "+v"(a), "+v"(b));
}
DEVFN float bcast32(float v, int srclane) {
  int r = __builtin_amdgcn_ds_bpermute(srclane * 4, __builtin_bit_cast(int, v));
  return __builtin_bit_cast(float, r);
}

// ================= fused prep: weight transposes + convx + tables + bias =================
__global__ __launch_bounds__(256) void prep_all(
    const float* __restrict__ Wq, const float* __restrict__ Wk, const float* __restrict__ Wv,
    const float* __restrict__ Wo, const float* __restrict__ bq, const float* __restrict__ bk,
    const float* __restrict__ bv, const float* __restrict__ x,
    unsigned short* __restrict__ Wqkvt, unsigned short* __restrict__ Wot,
    unsigned short* __restrict__ xb, float* __restrict__ cost, float* __restrict__ sint,
    float* __restrict__ bcat) {
  __shared__ float lds[32][33];
  const int bid = blockIdx.x, tid = threadIdx.x;
  if (bid < 10240) {
    const float* W; unsigned short* Wt; int ncols, bx, by;
    if (bid < 4096)      { W = Wq; Wt = Wqkvt;                        ncols = 2048; bx = bid & 63; by = bid >> 6; }
    else if (bid < 5120) { int l = bid - 4096; W = Wk; Wt = Wqkvt + (size_t)2048 * 2048; ncols = 512; bx = l & 15; by = l >> 4; }
    else if (bid < 6144) { int l = bid - 5120; W = Wv; Wt = Wqkvt + (size_t)2560 * 2048; ncols = 512; bx = l & 15; by = l >> 4; }
    else                 { int l = bid - 6144; W = Wo; Wt = Wot;      ncols = 2048; bx = l & 63; by = l >> 6; }
    int n0 = bx * 32, k0 = by * 32;
    int tx = tid & 31, ty = tid >> 5;
    #pragma unroll
    for (int i = 0; i < 4; i++) {
      int kr = ty + i * 8;
      lds[kr][tx] = W[(size_t)(k0 + kr) * ncols + n0 + tx];
    }
    __syncthreads();
    #pragma unroll
    for (int i = 0; i < 4; i++) {
      int nr = ty + i * 8;
      Wt[(size_t)(n0 + nr) * 2048 + k0 + tx] = f2bf(lds[tx][nr]);
    }
  } else if (bid < 14336) {
    int gid = (bid - 10240) * 256 + tid;
    const float4* xv = (const float4*)x;
    float4 a = xv[(size_t)gid * 2], b = xv[(size_t)gid * 2 + 1];
    short8 u;
    u[0] = (short)f2bf(a.x); u[1] = (short)f2bf(a.y); u[2] = (short)f2bf(a.z); u[3] = (short)f2bf(a.w);
    u[4] = (short)f2bf(b.x); u[5] = (short)f2bf(b.y); u[6] = (short)f2bf(b.z); u[7] = (short)f2bf(b.w);
    *(short8*)(xb + (size_t)gid * 8) = u;
  } else if (bid < 14592) {
    int gid = (bid - 14336) * 256 + tid;   // 65536
    int pos = gid >> 5, i = gid & 31;
    float theta = powf(10000.0f, -(float)(2 * i) / 64.0f);
    float ang = (float)pos * theta;
    cost[gid] = cosf(ang);
    sint[gid] = sinf(ang);
  } else {
    int i = (bid - 14592) * 256 + tid;     // 3072
    float v;
    if (i < 2048) v = bq[i];
    else if (i < 2560) v = bk[i - 2048];
    else v = bv[i - 2560];
    bcat[i] = v;
  }
}

// ================= fused scatter v2: vectorized ropeQ + ropeK + vtrans =================
__global__ __launch_bounds__(256) void scatter_all(
    const unsigned short* __restrict__ QKVb, const float* __restrict__ cost,
    const float* __restrict__ sint, const int* __restrict__ spp,
    unsigned short* __restrict__ QFr, unsigned short* __restrict__ KFr,
    unsigned short* __restrict__ VFr) {
  __shared__ __align__(16) unsigned short lds[64 * 128];
  const int bid = blockIdx.x, tid = threadIdx.x;
  if (bid < 5120) {
    int NH, colOff, gid, a, h, m;
    unsigned short* dst;
    float scale;
    if (bid < 4096) {
      NH = 16; colOff = 0; dst = QFr; scale = 0.12751743f;
      gid = bid * 256 + tid;
      a = gid & 15; h = (gid >> 4) & 15; m = gid >> 8;
    } else {
      NH = 4; colOff = 2048; dst = KFr; scale = 1.0f;
      gid = (bid - 4096) * 256 + tid;
      a = gid & 15; h = (gid >> 4) & 3; m = gid >> 6;
    }
    int t = m & 2047, b = m >> 11;
    short8 v = *(const short8*)(QKVb + (size_t)m * 3072 + colOff + h * 128 + 8 * a);
    float cs[4], sn[4];
    if (a < 8) {
      int pos = (spp[0] + t) & 2047;
      float4 c4 = *(const float4*)(cost + pos * 32 + 4 * a);
      float4 s4 = *(const float4*)(sint + pos * 32 + 4 * a);
      cs[0] = c4.x; cs[1] = c4.y; cs[2] = c4.z; cs[3] = c4.w;
      sn[0] = s4.x; sn[1] = s4.y; sn[2] = s4.z; sn[3] = s4.w;
    }
    short8 u;
    #pragma unroll
    for (int e = 0; e < 4; e++) {
      float xv = bf2f((unsigned short)v[2 * e]);
      float yv = bf2f((unsigned short)v[2 * e + 1]);
      float rx, ry;
      if (a < 8) {
        rx = xv * cs[e] - yv * sn[e];
        ry = xv * sn[e] + yv * cs[e];
      } else { rx = xv; ry = yv; }
      u[2 * e]     = (short)f2bf(rx * scale);
      u[2 * e + 1] = (short)f2bf(ry * scale);
    }
    size_t off = (size_t)(b * NH + h) * 262144 + (t >> 5) * 4096 + (a >> 1) * 512
               + (a & 1) * 256 + (t & 31) * 8;
    *(short8*)(dst + off) = u;
  } else {
    int l = bid - 5120;
    int t0 = (l & 31) * 64;
    int bk = l >> 5;
    const unsigned short* src = QKVb + (size_t)(bk >> 2) * 2048 * 3072 + 2560 + (bk & 3) * 128;
    #pragma unroll
    for (int c = 0; c < 4; c++) {
      int idx = c * 256 + tid;
      int tr = idx >> 4, dc = idx & 15;
      short8 v = *(const short8*)(src + (size_t)(t0 + tr) * 3072 + dc * 8);
      *(short8*)((char*)lds + tr * 256 + 16 * (dc ^ (tr >> 3))) = v;
    }
    __syncthreads();
    unsigned short* dstb = VFr + (size_t)bk * 262144;
    #pragma unroll
    for (int c2 = 0; c2 < 4; c2++) {
      int idx2 = c2 * 256 + tid;
      int tc = idx2 & 7, d = idx2 >> 3;
      short8 u;
      #pragma unroll
      for (int e = 0; e < 8; e++) {
        int t = 8 * tc + e;
        u[e] = *(const short*)((char*)lds + t * 256 + 16 * ((d >> 3) ^ tc) + (d & 7) * 2);
      }
      size_t off = (size_t)(t0 >> 6) * 8192 + ((d >> 5) * 4 + ((tc >> 1) & 3)) * 512
                 + (tc & 1) * 256 + (d & 31) * 8;
      *(short8*)(dstb + off) = u;
    }
  }
}

// ============ GEMM (best measured): 256x128 tile, BK=64, 8 waves, 3-buf, counted vmcnt ===
template<bool BF16OUT>
__global__ __launch_bounds__(512, 1) void gemm256(
    const unsigned short* __restrict__ A, const unsigned short* __restrict__ Bt,
    const float* __restrict__ bias, void* __restrict__ Cout, int M, int N, int K, int NTX) {
  __shared__ __align__(16) unsigned short lds[3][24576];   // 144 KB
  const int tid = threadIdx.x;
  const int lane = tid & 63, w = tid >> 6;
  const int wr = w >> 1, wc = w & 1;          // 4 M-waves x 2 N-waves; 64x64 per wave
  const int f = blockIdx.x;
  const int cpx = gridDim.x >> 3;
  const int fs = (f & 7) * cpx + (f >> 3);    // bijective XCD swizzle (grid % 8 == 0)
  const int m0 = (fs / NTX) * 256, n0 = (fs % NTX) * 128;
  const int NT = K >> 6;

  f32x4 acc[4][4];
  #pragma unroll
  for (int i = 0; i < 4; i++)
    #pragma unroll
    for (int j = 0; j < 4; j++)
      #pragma unroll
      for (int r = 0; r < 4; r++) acc[i][j][r] = 0.f;

  const int r8 = tid >> 3;
  const int c8 = (tid & 7) ^ (r8 & 7);
  const unsigned short* Asrc = A  + (size_t)(m0 + r8) * K + c8 * 8;
  const unsigned short* Bsrc = Bt + (size_t)(n0 + r8) * K + c8 * 8;
  const int woff = w * 512;

  auto STAGE = [&](int t) {
    unsigned short* bb = &lds[t % 3][0];
    const unsigned short* as = Asrc + t * 64;
    const unsigned short* bs = Bsrc + t * 64;
    #pragma unroll
    for (int l = 0; l < 2; l++) {
      __builtin_amdgcn_global_load_lds(
        (const __attribute__((address_space(1))) unsigned int*)(as + (size_t)l * 64 * K),
        (__attribute__((address_space(3))) unsigned int*)(bb + l * 4096 + woff), 16, 0, 0);
      __builtin_amdgcn_global_load_lds(
        (const __attribute__((address_space(1))) unsigned int*)(as + (size_t)(128 + l * 64) * K),
        (__attribute__((address_space(3))) unsigned int*)(bb + 8192 + l * 4096 + woff), 16, 0, 0);
      __builtin_amdgcn_global_load_lds(
        (const __attribute__((address_space(1))) unsigned int*)(bs + (size_t)l * 64 * K),
        (__attribute__((address_space(3))) unsigned int*)(bb + 16384 + l * 4096 + woff), 16, 0, 0);
    }
  };

  STAGE(0);
  STAGE(1);

  const int lr = lane & 15;
  const int q4 = lane >> 4;
  const int p7 = lane & 7;
  const int so0 = ((q4 ^ p7) * 8);
  const int so1 = (((q4 ^ 4) ^ p7) * 8);
  const int aBase = ((wr & 2) ? 8192 : 0) + ((wr & 1) * 64 + lr) * 64;
  const int bBase = 16384 + (wc * 64 + lr) * 64;

  for (int t = 0; t < NT; t++) {
    if (t + 1 < NT) asm volatile("s_waitcnt vmcnt(6)" ::: "memory");
    else            asm volatile("s_waitcnt vmcnt(0)" ::: "memory");
    __builtin_amdgcn_sched_barrier(0);
    __builtin_amdgcn_s_barrier();
    __builtin_amdgcn_sched_barrier(0);
    if (t + 2 < NT) STAGE(t + 2);
    const unsigned short* bb = &lds[t % 3][0];
    #pragma unroll
    for (int ks = 0; ks < 2; ks++) {
      const int so = ks ? so1 : so0;
      short8 af[4], bfr[4];
      #pragma unroll
      for (int mi = 0; mi < 4; mi++)
        af[mi] = *(const short8*)(bb + aBase + mi * 1024 + so);
      #pragma unroll
      for (int ni = 0; ni < 4; ni++)
        bfr[ni] = *(const short8*)(bb + bBase + ni * 1024 + so);
      __builtin_amdgcn_s_setprio(1);
      #pragma unroll
      for (int mi = 0; mi < 4; mi++)
        #pragma unroll
        for (int ni = 0; ni < 4; ni++)
          acc[mi][ni] = __builtin_amdgcn_mfma_f32_16x16x32_bf16(af[mi], bfr[ni], acc[mi][ni], 0, 0, 0);
      __builtin_amdgcn_s_setprio(0);
    }
  }

  const int cl = lane & 15, rq = lane >> 4;
  #pragma unroll
  for (int mi = 0; mi < 4; mi++) {
    #pragma unroll
    for (int ni = 0; ni < 4; ni++) {
      int gn = n0 + wc * 64 + ni * 16 + cl;
      float bv = bias[gn];
      #pragma unroll
      for (int r = 0; r < 4; r++) {
        int gm = m0 + wr * 64 + mi * 16 + rq * 4 + r;
        float v = acc[mi][ni][r] + bv;
        if (BF16OUT) ((unsigned short*)Cout)[(size_t)gm * N + gn] = f2bf(v);
        else ((float*)Cout)[(size_t)gm * N + gn] = v;
      }
    }
  }
}

// -------- flash attention v9 + T5 setprio on MFMA clusters (2 independent blocks/CU) -----
__global__ __launch_bounds__(256, 2) void attn_kernel(
    const unsigned short* __restrict__ QF, const unsigned short* __restrict__ KF,
    const unsigned short* __restrict__ VF, unsigned short* __restrict__ O) {
  __shared__ __align__(16) unsigned short Kl[2][8192];
  __shared__ __align__(16) unsigned short Vl[2][8192];

  const int tid = threadIdx.x;
  const int lane = tid & 63;
  const int w = tid >> 6;
  const int l31 = lane & 31;
  const int hf = lane >> 5;
  const int bid = blockIdx.x;
  const int g8 = bid & 7;
  const int b = g8 >> 2, kh = g8 & 3;
  const int h = kh * 4 + ((bid >> 3) & 3);
  const int qg = (bid < 256) ? (bid >> 5) : (15 - ((bid - 256) >> 5));
  const int qt = qg * 4 + w;
  const int qw = qt * 32;
  const int ntw = (qt >> 1) + 1;
  const int nbt = 2 * qg + 2;

  const unsigned short* qh  = QF + (size_t)(b * 16 + h) * 262144 + qt * 4096;
  const unsigned short* khp = KF + (size_t)(b * 4 + kh) * 262144;
  const unsigned short* vhp = VF + (size_t)(b * 4 + kh) * 262144;

  short8 qf[8];
  #pragma unroll
  for (int s = 0; s < 8; s++)
    qf[s] = *(const short8*)(qh + s * 512 + lane * 8);

  short8 ones;
  #pragma unroll
  for (int e = 0; e < 8; e++) ones[e] = (short)0x3F80;

  float m_r = -3.0e38f;
  f32x16 oacc[4];
  f32x16 lacc;
  #pragma unroll
  for (int dt = 0; dt < 4; dt++)
    #pragma unroll
    for (int r = 0; r < 16; r++) oacc[dt][r] = 0.f;
  #pragma unroll
  for (int r = 0; r < 16; r++) lacc[r] = 0.f;

  auto STAGE = [&](int buf, int kt) {
    #pragma unroll
    for (int c = 0; c < 4; c++) {
      const int sl = w * 4 + c;
      __builtin_amdgcn_global_load_lds(
        (const __attribute__((address_space(1))) unsigned int*)(khp + (size_t)kt * 8192 + sl * 512 + lane * 8),
        (__attribute__((address_space(3))) unsigned int*)(&Kl[buf][sl * 512]), 16, 0, 0);
      __builtin_amdgcn_global_load_lds(
        (const __attribute__((address_space(1))) unsigned int*)(vhp + (size_t)kt * 8192 + sl * 512 + lane * 8),
        (__attribute__((address_space(3))) unsigned int*)(&Vl[buf][sl * 512]), 16, 0, 0);
    }
  };

  STAGE(0, 0);
  int cur = 0;
  for (int kt = 0; kt < nbt; kt++) {
    __syncthreads();
    if (kt + 1 < nbt) STAGE(cur ^ 1, kt + 1);
    if (kt < ntw) {
      const int kv0 = kt * 64;
      const unsigned short* Kb = &Kl[cur][0];
      const unsigned short* Vb = &Vl[cur][0];
      f32x16 sc[2];
      {
        short8 kf0[8];
        #pragma unroll
        for (int s = 0; s < 8; s++)
          kf0[s] = *(const short8*)(Kb + s * 512 + lane * 8);
        #pragma unroll
        for (int r = 0; r < 16; r++) sc[0][r] = 0.f;
        __builtin_amdgcn_s_setprio(1);
        #pragma unroll
        for (int s = 0; s < 8; s++)
          sc[0] = __builtin_amdgcn_mfma_f32_32x32x16_bf16(kf0[s], qf[s], sc[0], 0, 0, 0);
        __builtin_amdgcn_s_setprio(0);
      }
      {
        short8 kf1[8];
        #pragma unroll
        for (int s = 0; s < 8; s++)
          kf1[s] = *(const short8*)(Kb + (8 + s) * 512 + lane * 8);
        #pragma unroll
        for (int r = 0; r < 16; r++) sc[1][r] = 0.f;
        __builtin_amdgcn_s_setprio(1);
        #pragma unroll
        for (int s = 0; s < 8; s++)
          sc[1] = __builtin_amdgcn_mfma_f32_32x32x16_bf16(kf1[s], qf[s], sc[1], 0, 0, 0);
        __builtin_amdgcn_s_setprio(0);
      }
      short8 vf[4][4];
      #pragma unroll
      for (int dt = 0; dt < 4; dt++)
        #pragma unroll
        for (int ks = 0; ks < 4; ks++)
          vf[dt][ks] = *(const short8*)(Vb + (dt * 4 + ks) * 512 + lane * 8);

      if (kv0 + 63 > qw) {
        #pragma unroll
        for (int ct = 0; ct < 2; ct++)
          #pragma unroll
          for (int r = 0; r < 16; r++) {
            int kg = kv0 + ct * 32 + (r & 3) + 8 * (r >> 2) + 4 * hf;
            if (kg > qw + l31) sc[ct][r] = -3.0e38f;
          }
      }
      float mx[16];
      #pragma unroll
      for (int r = 0; r < 16; r++) mx[r] = fmaxf(sc[0][r], sc[1][r]);
      #pragma unroll
      for (int s2 = 8; s2 >= 1; s2 >>= 1)
        #pragma unroll
        for (int i = 0; i < 8; i++) if (i < s2) mx[i] = fmaxf(mx[i], mx[i + s2]);
      float tm = fmaxf(mx[0], __shfl_xor(mx[0], 32));
      if (__any(tm > m_r + 8.0f)) {
        float mn = fmaxf(m_r, tm);
        float al = __builtin_amdgcn_exp2f(m_r - mn);
        m_r = mn;
        #pragma unroll
        for (int r = 0; r < 16; r++) {
          float alr = bcast32(al, (r & 3) + 8 * (r >> 2) + 4 * hf);
          #pragma unroll
          for (int dt = 0; dt < 4; dt++) oacc[dt][r] *= alr;
          lacc[r] *= alr;
        }
      }
      #pragma unroll
      for (int ct = 0; ct < 2; ct++)
        #pragma unroll
        for (int r = 0; r < 16; r++) sc[ct][r] = __builtin_amdgcn_exp2f(sc[ct][r] - m_r);

      short8 pa[4];
      #pragma unroll
      for (int ks = 0; ks < 4; ks++) {
        const int ct = ks >> 1, kb = (ks & 1) * 8;
        unsigned int A0 = cvtpk_bf16(sc[ct][kb + 0], sc[ct][kb + 1]);
        unsigned int A1 = cvtpk_bf16(sc[ct][kb + 2], sc[ct][kb + 3]);
        unsigned int B0 = cvtpk_bf16(sc[ct][kb + 4], sc[ct][kb + 5]);
        unsigned int B1 = cvtpk_bf16(sc[ct][kb + 6], sc[ct][kb + 7]);
        plswap32(A0, B0);
        plswap32(A1, B1);
        union { unsigned int wds[4]; short8 s8; } u;
        u.wds[0] = A0; u.wds[1] = A1; u.wds[2] = B0; u.wds[3] = B1;
        pa[ks] = u.s8;
      }
      __builtin_amdgcn_s_setprio(1);
      #pragma unroll
      for (int ks = 0; ks < 4; ks++)
        lacc = __builtin_amdgcn_mfma_f32_32x32x16_bf16(pa[ks], ones, lacc, 0, 0, 0);
      #pragma unroll
      for (int dt = 0; dt < 4; dt++)
        #pragma unroll
        for (int ks = 0; ks < 4; ks++)
          oacc[dt] = __builtin_amdgcn_mfma_f32_32x32x16_bf16(pa[ks], vf[dt][ks], oacc[dt], 0, 0, 0);
      __builtin_amdgcn_s_setprio(0);
    }
    cur ^= 1;
  }
  #pragma unroll
  for (int r = 0; r < 16; r++) {
    float inv = 1.0f / lacc[r];
    int rloc = (r & 3) + 8 * (r >> 2) + 4 * hf;
    int qgr = qw + rloc;
    unsigned short* orow = O + ((size_t)(b * 2048 + qgr)) * 2048 + h * 128;
    #pragma unroll
    for (int dt = 0; dt < 4; dt++)
      orow[dt * 32 + l31] = f2bf(oacc[dt][r] * inv);
  }
}

// ---------------- launch ----------------
extern "C" void kernel_launch(void* const* d_in, const int* in_sizes, int n_in,
                              void* d_out, int out_size, void* d_ws, size_t ws_size,
                              hipStream_t stream) {
  (void)in_sizes; (void)n_in; (void)out_size; (void)ws_size;
  const float* x  = (const float*)d_in[0];
  const float* Wq = (const float*)d_in[1];
  const float* bq = (const float*)d_in[2];
  const float* Wk = (const float*)d_in[3];
  const float* bk = (const float*)d_in[4];
  const float* Wv = (const float*)d_in[5];
  const float* bv = (const float*)d_in[6];
  const float* Wo = (const float*)d_in[7];
  const float* bo = (const float*)d_in[8];
  const int*   sp = (const int*)d_in[9];

  char* ws = (char*)d_ws;
  unsigned short* xb    = (unsigned short*)ws;                // 16,777,216 B (reused as Obuf)
  unsigned short* Wqkvt = (unsigned short*)(ws + 16777216);   // 12,582,912
  unsigned short* Wot   = (unsigned short*)(ws + 29360128);   //  8,388,608
  unsigned short* QKVb  = (unsigned short*)(ws + 37748736);   // 25,165,824 (bf16 [4096][3072])
  float* cost           = (float*)(ws + 62914560);            //    262,144
  float* sint           = (float*)(ws + 63176704);            //    262,144
  float* bcat           = (float*)(ws + 63438848);            //     12,288

  unsigned short* Obuf = xb;  // xb dead after GEMM1
  unsigned short* QFr = (unsigned short*)d_out;
  unsigned short* KFr = (unsigned short*)((char*)d_out + 16777216);
  unsigned short* VFr = (unsigned short*)((char*)d_out + 20971520);

  prep_all<<<dim3(14604), 256, 0, stream>>>(Wq, Wk, Wv, Wo, bq, bk, bv, x,
                                            Wqkvt, Wot, xb, cost, sint, bcat);
  gemm256<true><<<dim3(384), 512, 0, stream>>>(xb, Wqkvt, bcat, QKVb, 4096, 3072, 2048, 24);
  scatter_all<<<dim3(5376), 256, 0, stream>>>(QKVb, cost, sint, sp, QFr, KFr, VFr);
  attn_kernel<<<dim3(512), 256, 0, stream>>>(QFr, KFr, VFr, Obuf);
  gemm256<false><<<dim3(256), 512, 0, stream>>>(Obuf, Wot, bo, (float*)d_out, 4096, 2048, 2048, 16);
}

// Round 18
// 208.586 us; speedup vs baseline: 1.0096x; 1.0096x over previous
//
#include <hip/hip_runtime.h>

typedef __attribute__((ext_vector_type(8))) short short8;
typedef __attribute__((ext_vector_type(4))) float f32x4;
typedef __attribute__((ext_vector_type(16))) float f32x16;

#define DEVFN __device__ __forceinline__

DEVFN unsigned short f2bf(float f) {
  unsigned int u = __builtin_bit_cast(unsigned int, f);
  u += 0x7FFFu + ((u >> 16) & 1u);   // RNE
  return (unsigned short)(u >> 16);
}
DEVFN float bf2f(unsigned int u) { return __builtin_bit_cast(float, u << 16); }

DEVFN unsigned int cvtpk_bf16(float lo, float hi) {
  unsigned int d;
  asm("v_cvt_pk_bf16_f32 %0, %1, %2" : "=v"(d) : "v"(lo), "v"(hi));
  return d;
}
DEVFN void plswap32(unsigned int& a, unsigned int& b) {
  asm("v_permlane32_swap_b32 %0, %1" : "+v"(a), "+v"(b));
}
DEVFN float bcast32(float v, int srclane) {
  int r = __builtin_amdgcn_ds_bpermute(srclane * 4, __builtin_bit_cast(int, v));
  return __builtin_bit_cast(float, r);
}

// ================= fused prep: weight transposes + convx + tables + bias =================
__global__ __launch_bounds__(256) void prep_all(
    const float* __restrict__ Wq, const float* __restrict__ Wk, const float* __restrict__ Wv,
    const float* __restrict__ Wo, const float* __restrict__ bq, const float* __restrict__ bk,
    const float* __restrict__ bv, const float* __restrict__ x,
    unsigned short* __restrict__ Wqkvt, unsigned short* __restrict__ Wot,
    unsigned short* __restrict__ xb, float* __restrict__ cost, float* __restrict__ sint,
    float* __restrict__ bcat) {
  __shared__ float lds[32][33];
  const int bid = blockIdx.x, tid = threadIdx.x;
  if (bid < 10240) {
    const float* W; unsigned short* Wt; int ncols, bx, by;
    if (bid < 4096)      { W = Wq; Wt = Wqkvt;                        ncols = 2048; bx = bid & 63; by = bid >> 6; }
    else if (bid < 5120) { int l = bid - 4096; W = Wk; Wt = Wqkvt + (size_t)2048 * 2048; ncols = 512; bx = l & 15; by = l >> 4; }
    else if (bid < 6144) { int l = bid - 5120; W = Wv; Wt = Wqkvt + (size_t)2560 * 2048; ncols = 512; bx = l & 15; by = l >> 4; }
    else                 { int l = bid - 6144; W = Wo; Wt = Wot;      ncols = 2048; bx = l & 63; by = l >> 6; }
    int n0 = bx * 32, k0 = by * 32;
    int tx = tid & 31, ty = tid >> 5;
    #pragma unroll
    for (int i = 0; i < 4; i++) {
      int kr = ty + i * 8;
      lds[kr][tx] = W[(size_t)(k0 + kr) * ncols + n0 + tx];
    }
    __syncthreads();
    #pragma unroll
    for (int i = 0; i < 4; i++) {
      int nr = ty + i * 8;
      Wt[(size_t)(n0 + nr) * 2048 + k0 + tx] = f2bf(lds[tx][nr]);
    }
  } else if (bid < 14336) {
    int gid = (bid - 10240) * 256 + tid;
    const float4* xv = (const float4*)x;
    float4 a = xv[(size_t)gid * 2], b = xv[(size_t)gid * 2 + 1];
    short8 u;
    u[0] = (short)f2bf(a.x); u[1] = (short)f2bf(a.y); u[2] = (short)f2bf(a.z); u[3] = (short)f2bf(a.w);
    u[4] = (short)f2bf(b.x); u[5] = (short)f2bf(b.y); u[6] = (short)f2bf(b.z); u[7] = (short)f2bf(b.w);
    *(short8*)(xb + (size_t)gid * 8) = u;
  } else if (bid < 14592) {
    int gid = (bid - 14336) * 256 + tid;   // 65536
    int pos = gid >> 5, i = gid & 31;
    float theta = powf(10000.0f, -(float)(2 * i) / 64.0f);
    float ang = (float)pos * theta;
    cost[gid] = cosf(ang);
    sint[gid] = sinf(ang);
  } else {
    int i = (bid - 14592) * 256 + tid;     // 3072
    float v;
    if (i < 2048) v = bq[i];
    else if (i < 2560) v = bk[i - 2048];
    else v = bv[i - 2560];
    bcat[i] = v;
  }
}

// ================= fused scatter v2: vectorized ropeQ + ropeK + vtrans =================
__global__ __launch_bounds__(256) void scatter_all(
    const unsigned short* __restrict__ QKVb, const float* __restrict__ cost,
    const float* __restrict__ sint, const int* __restrict__ spp,
    unsigned short* __restrict__ QFr, unsigned short* __restrict__ KFr,
    unsigned short* __restrict__ VFr) {
  __shared__ __align__(16) unsigned short lds[64 * 128];
  const int bid = blockIdx.x, tid = threadIdx.x;
  if (bid < 5120) {
    int NH, colOff, gid, a, h, m;
    unsigned short* dst;
    float scale;
    if (bid < 4096) {
      NH = 16; colOff = 0; dst = QFr; scale = 0.12751743f;
      gid = bid * 256 + tid;
      a = gid & 15; h = (gid >> 4) & 15; m = gid >> 8;
    } else {
      NH = 4; colOff = 2048; dst = KFr; scale = 1.0f;
      gid = (bid - 4096) * 256 + tid;
      a = gid & 15; h = (gid >> 4) & 3; m = gid >> 6;
    }
    int t = m & 2047, b = m >> 11;
    short8 v = *(const short8*)(QKVb + (size_t)m * 3072 + colOff + h * 128 + 8 * a);
    float cs[4], sn[4];
    if (a < 8) {
      int pos = (spp[0] + t) & 2047;
      float4 c4 = *(const float4*)(cost + pos * 32 + 4 * a);
      float4 s4 = *(const float4*)(sint + pos * 32 + 4 * a);
      cs[0] = c4.x; cs[1] = c4.y; cs[2] = c4.z; cs[3] = c4.w;
      sn[0] = s4.x; sn[1] = s4.y; sn[2] = s4.z; sn[3] = s4.w;
    }
    short8 u;
    #pragma unroll
    for (int e = 0; e < 4; e++) {
      float xv = bf2f((unsigned short)v[2 * e]);
      float yv = bf2f((unsigned short)v[2 * e + 1]);
      float rx, ry;
      if (a < 8) {
        rx = xv * cs[e] - yv * sn[e];
        ry = xv * sn[e] + yv * cs[e];
      } else { rx = xv; ry = yv; }
      u[2 * e]     = (short)f2bf(rx * scale);
      u[2 * e + 1] = (short)f2bf(ry * scale);
    }
    size_t off = (size_t)(b * NH + h) * 262144 + (t >> 5) * 4096 + (a >> 1) * 512
               + (a & 1) * 256 + (t & 31) * 8;
    *(short8*)(dst + off) = u;
  } else {
    int l = bid - 5120;
    int t0 = (l & 31) * 64;
    int bk = l >> 5;
    const unsigned short* src = QKVb + (size_t)(bk >> 2) * 2048 * 3072 + 2560 + (bk & 3) * 128;
    #pragma unroll
    for (int c = 0; c < 4; c++) {
      int idx = c * 256 + tid;
      int tr = idx >> 4, dc = idx & 15;
      short8 v = *(const short8*)(src + (size_t)(t0 + tr) * 3072 + dc * 8);
      *(short8*)((char*)lds + tr * 256 + 16 * (dc ^ (tr >> 3))) = v;
    }
    __syncthreads();
    unsigned short* dstb = VFr + (size_t)bk * 262144;
    #pragma unroll
    for (int c2 = 0; c2 < 4; c2++) {
      int idx2 = c2 * 256 + tid;
      int tc = idx2 & 7, d = idx2 >> 3;
      short8 u;
      #pragma unroll
      for (int e = 0; e < 8; e++) {
        int t = 8 * tc + e;
        u[e] = *(const short*)((char*)lds + t * 256 + 16 * ((d >> 3) ^ tc) + (d & 7) * 2);
      }
      size_t off = (size_t)(t0 >> 6) * 8192 + ((d >> 5) * 4 + ((tc >> 1) & 3)) * 512
                 + (tc & 1) * 256 + (d & 31) * 8;
      *(short8*)(dstb + off) = u;
    }
  }
}

// ============ GEMM (best measured): 256x128 tile, BK=64, 8 waves, 3-buf, counted vmcnt ===
template<bool BF16OUT>
__global__ __launch_bounds__(512, 1) void gemm256(
    const unsigned short* __restrict__ A, const unsigned short* __restrict__ Bt,
    const float* __restrict__ bias, void* __restrict__ Cout, int M, int N, int K, int NTX) {
  __shared__ __align__(16) unsigned short lds[3][24576];   // 144 KB
  const int tid = threadIdx.x;
  const int lane = tid & 63, w = tid >> 6;
  const int wr = w >> 1, wc = w & 1;          // 4 M-waves x 2 N-waves; 64x64 per wave
  const int f = blockIdx.x;
  const int cpx = gridDim.x >> 3;
  const int fs = (f & 7) * cpx + (f >> 3);    // bijective XCD swizzle (grid % 8 == 0)
  const int m0 = (fs / NTX) * 256, n0 = (fs % NTX) * 128;
  const int NT = K >> 6;

  f32x4 acc[4][4];
  #pragma unroll
  for (int i = 0; i < 4; i++)
    #pragma unroll
    for (int j = 0; j < 4; j++)
      #pragma unroll
      for (int r = 0; r < 4; r++) acc[i][j][r] = 0.f;

  const int r8 = tid >> 3;
  const int c8 = (tid & 7) ^ (r8 & 7);
  const unsigned short* Asrc = A  + (size_t)(m0 + r8) * K + c8 * 8;
  const unsigned short* Bsrc = Bt + (size_t)(n0 + r8) * K + c8 * 8;
  const int woff = w * 512;

  auto STAGE = [&](int t) {
    unsigned short* bb = &lds[t % 3][0];
    const unsigned short* as = Asrc + t * 64;
    const unsigned short* bs = Bsrc + t * 64;
    #pragma unroll
    for (int l = 0; l < 2; l++) {
      __builtin_amdgcn_global_load_lds(
        (const __attribute__((address_space(1))) unsigned int*)(as + (size_t)l * 64 * K),
        (__attribute__((address_space(3))) unsigned int*)(bb + l * 4096 + woff), 16, 0, 0);
      __builtin_amdgcn_global_load_lds(
        (const __attribute__((address_space(1))) unsigned int*)(as + (size_t)(128 + l * 64) * K),
        (__attribute__((address_space(3))) unsigned int*)(bb + 8192 + l * 4096 + woff), 16, 0, 0);
      __builtin_amdgcn_global_load_lds(
        (const __attribute__((address_space(1))) unsigned int*)(bs + (size_t)l * 64 * K),
        (__attribute__((address_space(3))) unsigned int*)(bb + 16384 + l * 4096 + woff), 16, 0, 0);
    }
  };

  STAGE(0);
  STAGE(1);

  const int lr = lane & 15;
  const int q4 = lane >> 4;
  const int p7 = lane & 7;
  const int so0 = ((q4 ^ p7) * 8);
  const int so1 = (((q4 ^ 4) ^ p7) * 8);
  const int aBase = ((wr & 2) ? 8192 : 0) + ((wr & 1) * 64 + lr) * 64;
  const int bBase = 16384 + (wc * 64 + lr) * 64;

  for (int t = 0; t < NT; t++) {
    if (t + 1 < NT) asm volatile("s_waitcnt vmcnt(6)" ::: "memory");
    else            asm volatile("s_waitcnt vmcnt(0)" ::: "memory");
    __builtin_amdgcn_sched_barrier(0);
    __builtin_amdgcn_s_barrier();
    __builtin_amdgcn_sched_barrier(0);
    if (t + 2 < NT) STAGE(t + 2);
    const unsigned short* bb = &lds[t % 3][0];
    #pragma unroll
    for (int ks = 0; ks < 2; ks++) {
      const int so = ks ? so1 : so0;
      short8 af[4], bfr[4];
      #pragma unroll
      for (int mi = 0; mi < 4; mi++)
        af[mi] = *(const short8*)(bb + aBase + mi * 1024 + so);
      #pragma unroll
      for (int ni = 0; ni < 4; ni++)
        bfr[ni] = *(const short8*)(bb + bBase + ni * 1024 + so);
      __builtin_amdgcn_s_setprio(1);
      #pragma unroll
      for (int mi = 0; mi < 4; mi++)
        #pragma unroll
        for (int ni = 0; ni < 4; ni++)
          acc[mi][ni] = __builtin_amdgcn_mfma_f32_16x16x32_bf16(af[mi], bfr[ni], acc[mi][ni], 0, 0, 0);
      __builtin_amdgcn_s_setprio(0);
    }
  }

  const int cl = lane & 15, rq = lane >> 4;
  #pragma unroll
  for (int mi = 0; mi < 4; mi++) {
    #pragma unroll
    for (int ni = 0; ni < 4; ni++) {
      int gn = n0 + wc * 64 + ni * 16 + cl;
      float bv = bias[gn];
      #pragma unroll
      for (int r = 0; r < 4; r++) {
        int gm = m0 + wr * 64 + mi * 16 + rq * 4 + r;
        float v = acc[mi][ni][r] + bv;
        if (BF16OUT) ((unsigned short*)Cout)[(size_t)gm * N + gn] = f2bf(v);
        else ((float*)Cout)[(size_t)gm * N + gn] = v;
      }
    }
  }
}

// ---------------- flash attention v9 (best measured): LDS-shared K/V dbuf, 4 waves ------
__global__ __launch_bounds__(256, 2) void attn_kernel(
    const unsigned short* __restrict__ QF, const unsigned short* __restrict__ KF,
    const unsigned short* __restrict__ VF, unsigned short* __restrict__ O) {
  __shared__ __align__(16) unsigned short Kl[2][8192];
  __shared__ __align__(16) unsigned short Vl[2][8192];

  const int tid = threadIdx.x;
  const int lane = tid & 63;
  const int w = tid >> 6;
  const int l31 = lane & 31;
  const int hf = lane >> 5;
  const int bid = blockIdx.x;
  const int g8 = bid & 7;
  const int b = g8 >> 2, kh = g8 & 3;
  const int h = kh * 4 + ((bid >> 3) & 3);
  const int qg = (bid < 256) ? (bid >> 5) : (15 - ((bid - 256) >> 5));
  const int qt = qg * 4 + w;
  const int qw = qt * 32;
  const int ntw = (qt >> 1) + 1;
  const int nbt = 2 * qg + 2;

  const unsigned short* qh  = QF + (size_t)(b * 16 + h) * 262144 + qt * 4096;
  const unsigned short* khp = KF + (size_t)(b * 4 + kh) * 262144;
  const unsigned short* vhp = VF + (size_t)(b * 4 + kh) * 262144;

  short8 qf[8];
  #pragma unroll
  for (int s = 0; s < 8; s++)
    qf[s] = *(const short8*)(qh + s * 512 + lane * 8);

  short8 ones;
  #pragma unroll
  for (int e = 0; e < 8; e++) ones[e] = (short)0x3F80;

  float m_r = -3.0e38f;
  f32x16 oacc[4];
  f32x16 lacc;
  #pragma unroll
  for (int dt = 0; dt < 4; dt++)
    #pragma unroll
    for (int r = 0; r < 16; r++) oacc[dt][r] = 0.f;
  #pragma unroll
  for (int r = 0; r < 16; r++) lacc[r] = 0.f;

  auto STAGE = [&](int buf, int kt) {
    #pragma unroll
    for (int c = 0; c < 4; c++) {
      const int sl = w * 4 + c;
      __builtin_amdgcn_global_load_lds(
        (const __attribute__((address_space(1))) unsigned int*)(khp + (size_t)kt * 8192 + sl * 512 + lane * 8),
        (__attribute__((address_space(3))) unsigned int*)(&Kl[buf][sl * 512]), 16, 0, 0);
      __builtin_amdgcn_global_load_lds(
        (const __attribute__((address_space(1))) unsigned int*)(vhp + (size_t)kt * 8192 + sl * 512 + lane * 8),
        (__attribute__((address_space(3))) unsigned int*)(&Vl[buf][sl * 512]), 16, 0, 0);
    }
  };

  STAGE(0, 0);
  int cur = 0;
  for (int kt = 0; kt < nbt; kt++) {
    __syncthreads();
    if (kt + 1 < nbt) STAGE(cur ^ 1, kt + 1);
    if (kt < ntw) {
      const int kv0 = kt * 64;
      const unsigned short* Kb = &Kl[cur][0];
      const unsigned short* Vb = &Vl[cur][0];
      f32x16 sc[2];
      {
        short8 kf0[8];
        #pragma unroll
        for (int s = 0; s < 8; s++)
          kf0[s] = *(const short8*)(Kb + s * 512 + lane * 8);
        #pragma unroll
        for (int r = 0; r < 16; r++) sc[0][r] = 0.f;
        #pragma unroll
        for (int s = 0; s < 8; s++)
          sc[0] = __builtin_amdgcn_mfma_f32_32x32x16_bf16(kf0[s], qf[s], sc[0], 0, 0, 0);
      }
      {
        short8 kf1[8];
        #pragma unroll
        for (int s = 0; s < 8; s++)
          kf1[s] = *(const short8*)(Kb + (8 + s) * 512 + lane * 8);
        #pragma unroll
        for (int r = 0; r < 16; r++) sc[1][r] = 0.f;
        #pragma unroll
        for (int s = 0; s < 8; s++)
          sc[1] = __builtin_amdgcn_mfma_f32_32x32x16_bf16(kf1[s], qf[s], sc[1], 0, 0, 0);
      }
      short8 vf[4][4];
      #pragma unroll
      for (int dt = 0; dt < 4; dt++)
        #pragma unroll
        for (int ks = 0; ks < 4; ks++)
          vf[dt][ks] = *(const short8*)(Vb + (dt * 4 + ks) * 512 + lane * 8);

      if (kv0 + 63 > qw) {
        #pragma unroll
        for (int ct = 0; ct < 2; ct++)
          #pragma unroll
          for (int r = 0; r < 16; r++) {
            int kg = kv0 + ct * 32 + (r & 3) + 8 * (r >> 2) + 4 * hf;
            if (kg > qw + l31) sc[ct][r] = -3.0e38f;
          }
      }
      float mx[16];
      #pragma unroll
      for (int r = 0; r < 16; r++) mx[r] = fmaxf(sc[0][r], sc[1][r]);
      #pragma unroll
      for (int s2 = 8; s2 >= 1; s2 >>= 1)
        #pragma unroll
        for (int i = 0; i < 8; i++) if (i < s2) mx[i] = fmaxf(mx[i], mx[i + s2]);
      float tm = fmaxf(mx[0], __shfl_xor(mx[0], 32));
      if (__any(tm > m_r + 8.0f)) {
        float mn = fmaxf(m_r, tm);
        float al = __builtin_amdgcn_exp2f(m_r - mn);
        m_r = mn;
        #pragma unroll
        for (int r = 0; r < 16; r++) {
          float alr = bcast32(al, (r & 3) + 8 * (r >> 2) + 4 * hf);
          #pragma unroll
          for (int dt = 0; dt < 4; dt++) oacc[dt][r] *= alr;
          lacc[r] *= alr;
        }
      }
      #pragma unroll
      for (int ct = 0; ct < 2; ct++)
        #pragma unroll
        for (int r = 0; r < 16; r++) sc[ct][r] = __builtin_amdgcn_exp2f(sc[ct][r] - m_r);

      short8 pa[4];
      #pragma unroll
      for (int ks = 0; ks < 4; ks++) {
        const int ct = ks >> 1, kb = (ks & 1) * 8;
        unsigned int A0 = cvtpk_bf16(sc[ct][kb + 0], sc[ct][kb + 1]);
        unsigned int A1 = cvtpk_bf16(sc[ct][kb + 2], sc[ct][kb + 3]);
        unsigned int B0 = cvtpk_bf16(sc[ct][kb + 4], sc[ct][kb + 5]);
        unsigned int B1 = cvtpk_bf16(sc[ct][kb + 6], sc[ct][kb + 7]);
        plswap32(A0, B0);
        plswap32(A1, B1);
        union { unsigned int wds[4]; short8 s8; } u;
        u.wds[0] = A0; u.wds[1] = A1; u.wds[2] = B0; u.wds[3] = B1;
        pa[ks] = u.s8;
      }
      #pragma unroll
      for (int ks = 0; ks < 4; ks++)
        lacc = __builtin_amdgcn_mfma_f32_32x32x16_bf16(pa[ks], ones, lacc, 0, 0, 0);
      #pragma unroll
      for (int dt = 0; dt < 4; dt++)
        #pragma unroll
        for (int ks = 0; ks < 4; ks++)
          oacc[dt] = __builtin_amdgcn_mfma_f32_32x32x16_bf16(pa[ks], vf[dt][ks], oacc[dt], 0, 0, 0);
    }
    cur ^= 1;
  }
  #pragma unroll
  for (int r = 0; r < 16; r++) {
    float inv = 1.0f / lacc[r];
    int rloc = (r & 3) + 8 * (r >> 2) + 4 * hf;
    int qgr = qw + rloc;
    unsigned short* orow = O + ((size_t)(b * 2048 + qgr)) * 2048 + h * 128;
    #pragma unroll
    for (int dt = 0; dt < 4; dt++)
      orow[dt * 32 + l31] = f2bf(oacc[dt][r] * inv);
  }
}

// ---------------- launch ----------------
extern "C" void kernel_launch(void* const* d_in, const int* in_sizes, int n_in,
                              void* d_out, int out_size, void* d_ws, size_t ws_size,
                              hipStream_t stream) {
  (void)in_sizes; (void)n_in; (void)out_size; (void)ws_size;
  const float* x  = (const float*)d_in[0];
  const float* Wq = (const float*)d_in[1];
  const float* bq = (const float*)d_in[2];
  const float* Wk = (const float*)d_in[3];
  const float* bk = (const float*)d_in[4];
  const float* Wv = (const float*)d_in[5];
  const float* bv = (const float*)d_in[6];
  const float* Wo = (const float*)d_in[7];
  const float* bo = (const float*)d_in[8];
  const int*   sp = (const int*)d_in[9];

  char* ws = (char*)d_ws;
  unsigned short* xb    = (unsigned short*)ws;                // 16,777,216 B (reused as Obuf)
  unsigned short* Wqkvt = (unsigned short*)(ws + 16777216);   // 12,582,912
  unsigned short* Wot   = (unsigned short*)(ws + 29360128);   //  8,388,608
  unsigned short* QKVb  = (unsigned short*)(ws + 37748736);   // 25,165,824 (bf16 [4096][3072])
  float* cost           = (float*)(ws + 62914560);            //    262,144
  float* sint           = (float*)(ws + 63176704);            //    262,144
  float* bcat           = (float*)(ws + 63438848);            //     12,288

  unsigned short* Obuf = xb;  // xb dead after GEMM1
  unsigned short* QFr = (unsigned short*)d_out;
  unsigned short* KFr = (unsigned short*)((char*)d_out + 16777216);
  unsigned short* VFr = (unsigned short*)((char*)d_out + 20971520);

  prep_all<<<dim3(14604), 256, 0, stream>>>(Wq, Wk, Wv, Wo, bq, bk, bv, x,
                                            Wqkvt, Wot, xb, cost, sint, bcat);
  gemm256<true><<<dim3(384), 512, 0, stream>>>(xb, Wqkvt, bcat, QKVb, 4096, 3072, 2048, 24);
  scatter_all<<<dim3(5376), 256, 0, stream>>>(QKVb, cost, sint, sp, QFr, KFr, VFr);
  attn_kernel<<<dim3(512), 256, 0, stream>>>(QFr, KFr, VFr, Obuf);
  gemm256<false><<<dim3(256), 512, 0, stream>>>(Obuf, Wot, bo, (float*)d_out, 4096, 2048, 2048, 16);
}